// Round 1
// baseline (1408.552 us; speedup 1.0000x reference)
//
#include <hip/hip_runtime.h>
#include <stdint.h>

#define N_  32
#define C_  512
#define T_  2048
#define NB  1024
#define NT  (N_ * T_)          // 65536
#define BM  128
#define BN  128
#define BK  16
#define AS_S 128               // As leading stride (floats)
#define BS_S 132               // Bs leading stride (+4 pad -> ~2-way banks)
#define GB_S 129               // gather buffer stride (+1 pad -> conflict-free)

// ---------------- init: zero commit accumulator + counts ----------------
__global__ void k_init(float* wsf) {
    int t = blockIdx.x * 256 + threadIdx.x;
    if (t < 1032) wsf[t] = 0.0f;   // wsf[0]=commit, wsf[8..1031]=counts(int bits)
}

// ---------------- codebook row norms ----------------
__global__ void k_codenorm(const float* __restrict__ cb, float* __restrict__ cnorm) {
    int j = blockIdx.x * 256 + threadIdx.x;   // grid 4*256 = 1024
    const float* r = cb + (size_t)j * C_;
    float s = 0.f;
    for (int i = 0; i < C_; i += 4) {
        float4 v = *(const float4*)&r[i];
        s = fmaf(v.x, v.x, s); s = fmaf(v.y, v.y, s);
        s = fmaf(v.z, v.z, s); s = fmaf(v.w, v.w, s);
    }
    cnorm[j] = s;
}

// ---------------- main: GEMM + streaming argmin + gather + commit ----------------
__global__ __launch_bounds__(256, 4)
void k_main(const float* __restrict__ x, const float* __restrict__ cb,
            const float* __restrict__ cnorm, float* __restrict__ out,
            float* __restrict__ commitAcc, int* __restrict__ counts) {
    __shared__ float smem[8256];            // 33 KB: As+Bs during GEMM, gbuf in epilogue
    __shared__ unsigned long long rmin[BM];
    __shared__ int sidx[BM];
    __shared__ float red[4];

    float* As = smem;                        // [BK][AS_S]
    float* Bs = smem + BK * AS_S;            // [BK][BS_S]

    const int bid = blockIdx.x;              // 0..511
    const int n   = bid >> 4;
    const int t0  = (bid & 15) << 7;         // *128
    const int tid = threadIdx.x;
    const int tx  = tid & 15;
    const int ty  = tid >> 4;

    if (tid < BM) rmin[tid] = 0xFFFFFFFFFFFFFFFFull;

    const size_t xbase = (size_t)n * C_ * T_ + t0;

    for (int ch = 0; ch < NB / BN; ++ch) {
        const int j0 = ch * BN;
        float acc[2][2][4][4];
        #pragma unroll
        for (int a0 = 0; a0 < 2; ++a0)
            #pragma unroll
            for (int a1 = 0; a1 < 2; ++a1)
                #pragma unroll
                for (int a2 = 0; a2 < 4; ++a2)
                    #pragma unroll
                    for (int a3 = 0; a3 < 4; ++a3) acc[a0][a1][a2][a3] = 0.f;

        for (int kb = 0; kb < C_ / BK; ++kb) {
            const int k0 = kb * BK;
            __syncthreads();
            {   // A tile: As[kk][m] = x[n][k0+kk][t0+m]  (coalesced float4)
                const int kk = tid >> 5;             // 0..7
                const int m4 = (tid & 31) << 2;      // 0..124
                float4 a0v = *(const float4*)&x[xbase + (size_t)(k0 + kk) * T_ + m4];
                float4 a1v = *(const float4*)&x[xbase + (size_t)(k0 + kk + 8) * T_ + m4];
                *(float4*)&As[kk * AS_S + m4] = a0v;
                *(float4*)&As[(kk + 8) * AS_S + m4] = a1v;
                // B tile (transposed store): Bs[k][j] = cb[j0+j][k0+k]
                const int j  = tid >> 2;             // 0..63
                const int kq = (tid & 3) << 2;       // 0,4,8,12
                float4 b0v = *(const float4*)&cb[(size_t)(j0 + j) * C_ + k0 + kq];
                float4 b1v = *(const float4*)&cb[(size_t)(j0 + j + 64) * C_ + k0 + kq];
                Bs[(kq + 0) * BS_S + j] = b0v.x;
                Bs[(kq + 1) * BS_S + j] = b0v.y;
                Bs[(kq + 2) * BS_S + j] = b0v.z;
                Bs[(kq + 3) * BS_S + j] = b0v.w;
                Bs[(kq + 0) * BS_S + j + 64] = b1v.x;
                Bs[(kq + 1) * BS_S + j + 64] = b1v.y;
                Bs[(kq + 2) * BS_S + j + 64] = b1v.z;
                Bs[(kq + 3) * BS_S + j + 64] = b1v.w;
            }
            __syncthreads();
            #pragma unroll
            for (int kk = 0; kk < BK; ++kk) {
                float4 aL = *(const float4*)&As[kk * AS_S + (ty << 2)];
                float4 aH = *(const float4*)&As[kk * AS_S + 64 + (ty << 2)];
                float4 bL = *(const float4*)&Bs[kk * BS_S + (tx << 2)];
                float4 bH = *(const float4*)&Bs[kk * BS_S + 64 + (tx << 2)];
                float av[2][4] = {{aL.x, aL.y, aL.z, aL.w}, {aH.x, aH.y, aH.z, aH.w}};
                float bv[2][4] = {{bL.x, bL.y, bL.z, bL.w}, {bH.x, bH.y, bH.z, bH.w}};
                #pragma unroll
                for (int ih = 0; ih < 2; ++ih)
                    #pragma unroll
                    for (int i = 0; i < 4; ++i)
                        #pragma unroll
                        for (int jh = 0; jh < 2; ++jh)
                            #pragma unroll
                            for (int j = 0; j < 4; ++j)
                                acc[ih][jh][i][j] = fmaf(av[ih][i], bv[jh][j], acc[ih][jh][i][j]);
            }
        }

        // scores = cnorm[code] - 2*dot ; streaming argmin (tie -> lowest idx)
        float cnj[2][4];
        #pragma unroll
        for (int jh = 0; jh < 2; ++jh)
            #pragma unroll
            for (int j = 0; j < 4; ++j)
                cnj[jh][j] = cnorm[j0 + jh * 64 + (tx << 2) + j];

        #pragma unroll
        for (int ih = 0; ih < 2; ++ih) {
            #pragma unroll
            for (int i = 0; i < 4; ++i) {
                const int row = ih * 64 + (ty << 2) + i;
                unsigned long long best = 0xFFFFFFFFFFFFFFFFull;
                #pragma unroll
                for (int jh = 0; jh < 2; ++jh) {
                    #pragma unroll
                    for (int j = 0; j < 4; ++j) {
                        const int code = j0 + jh * 64 + (tx << 2) + j;
                        float s = fmaf(-2.0f, acc[ih][jh][i][j], cnj[jh][j]);
                        unsigned u = __float_as_uint(s);
                        u = (u & 0x80000000u) ? ~u : (u | 0x80000000u);
                        unsigned long long key =
                            ((unsigned long long)u << 32) | (unsigned)code;
                        best = key < best ? key : best;
                    }
                }
                #pragma unroll
                for (int off = 8; off; off >>= 1) {
                    unsigned long long o = __shfl_down(best, off, 16);
                    best = o < best ? o : best;
                }
                if (tx == 0) {   // single writer per row -> no atomic needed
                    unsigned long long cur = rmin[row];
                    rmin[row] = best < cur ? best : cur;
                }
            }
        }
    }

    __syncthreads();
    if (tid < BM) {
        int code = (int)(rmin[tid] & 0xFFFFFFFFull);
        sidx[tid] = code;
        atomicAdd(&counts[code], 1);
    }
    __syncthreads();

    // epilogue: gather codebook rows (LDS-transposed), write out, commit loss
    float* gbuf = smem;                      // [64][GB_S]
    const int tl   = tid >> 1;               // 0..127
    const int half = tid & 1;
    const int tcol  = tid & 127;
    const int chalf = tid >> 7;              // 0/1
    float commit = 0.f;

    for (int c0 = 0; c0 < C_; c0 += 64) {
        __syncthreads();                     // gbuf reuse safe
        const int code = sidx[tl];
        const float* src = &cb[(size_t)code * C_ + c0 + half * 32];
        #pragma unroll
        for (int q = 0; q < 8; ++q) {
            float4 v = *(const float4*)&src[q * 4];
            const int cc = half * 32 + q * 4;
            gbuf[(cc + 0) * GB_S + tl] = v.x;
            gbuf[(cc + 1) * GB_S + tl] = v.y;
            gbuf[(cc + 2) * GB_S + tl] = v.z;
            gbuf[(cc + 3) * GB_S + tl] = v.w;
        }
        __syncthreads();
        #pragma unroll 8
        for (int i = 0; i < 32; ++i) {
            const int cc = i * 2 + chalf;
            const size_t gidx = xbase + (size_t)(c0 + cc) * T_ + tcol;
            float g  = gbuf[cc * GB_S + tcol];
            float xv = x[gidx];
            out[gidx] = g;
            float d = xv - g;
            commit = fmaf(d, d, commit);
        }
    }

    #pragma unroll
    for (int off = 32; off; off >>= 1) commit += __shfl_down(commit, off, 64);
    if ((tid & 63) == 0) red[tid >> 6] = commit;
    __syncthreads();
    if (tid == 0) atomicAdd(commitAcc, red[0] + red[1] + red[2] + red[3]);
}

// ---------------- finalize: perplexity + commit scalars ----------------
__global__ void k_final(const int* __restrict__ counts,
                        const float* __restrict__ commitAcc,
                        float* __restrict__ out) {
    __shared__ float red[4];
    int tid = threadIdx.x;
    float s = 0.f;
    for (int j = tid; j < NB; j += 256) {
        float p = (float)counts[j] * (1.0f / (float)NT);
        s += p * logf(p + 1e-7f);
    }
    #pragma unroll
    for (int off = 32; off; off >>= 1) s += __shfl_down(s, off, 64);
    if ((tid & 63) == 0) red[tid >> 6] = s;
    __syncthreads();
    if (tid == 0) {
        float H = red[0] + red[1] + red[2] + red[3];
        out[(size_t)NT * C_]     = commitAcc[0] * (1.0f / ((float)NT * (float)C_));
        out[(size_t)NT * C_ + 1] = expf(-H);
    }
}

extern "C" void kernel_launch(void* const* d_in, const int* in_sizes, int n_in,
                              void* d_out, int out_size, void* d_ws, size_t ws_size,
                              hipStream_t stream) {
    const float* x  = (const float*)d_in[0];   // (32, 512, 2048)
    const float* cb = (const float*)d_in[1];   // (1024, 512)
    float* out = (float*)d_out;                // 33554432 + 2
    float* wsf = (float*)d_ws;
    float* commitAcc = wsf;                    // wsf[0]
    int*   counts    = (int*)(wsf + 8);        // wsf[8..1031]
    float* cnorm     = wsf + 1032;             // wsf[1032..2055]

    k_init<<<5, 256, 0, stream>>>(wsf);
    k_codenorm<<<4, 256, 0, stream>>>(cb, cnorm);
    k_main<<<512, 256, 0, stream>>>(x, cb, cnorm, out, commitAcc, counts);
    k_final<<<1, 256, 0, stream>>>(counts, commitAcc, out);
}

// Round 2
// 550.430 us; speedup vs baseline: 2.5590x; 2.5590x over previous
//
#include <hip/hip_runtime.h>
#include <stdint.h>

#define N_  32
#define C_  512
#define T_  2048
#define NB  1024
#define NT  (N_ * T_)          // 65536
#define GB_S 129               // gather buffer stride (+1 pad)

typedef _Float16 h8 __attribute__((ext_vector_type(8)));
typedef _Float16 h4 __attribute__((ext_vector_type(4)));
typedef float    f4 __attribute__((ext_vector_type(4)));

// ws byte offsets
#define WS_COMMIT   0
#define WS_COUNTS   64
#define WS_CNORM    4224
#define WS_RMIN     8320
#define WS_CBH      532608
#define WS_CBL      1581184
#define WS_XTH      2629760
#define WS_XTL      69738624
#define WS_NEED     136847488ull

__device__ __forceinline__ void gll16(const void* g, void* l) {
    __builtin_amdgcn_global_load_lds((const __attribute__((address_space(1))) void*)g,
                                     (__attribute__((address_space(3))) void*)l, 16, 0, 0);
}

// ---------------- init (fast path): zero commit+counts, rmin = ~0 ----------------
__global__ void k_initA(unsigned* ws32, unsigned long long* rmin) {
    int g = blockIdx.x * 256 + threadIdx.x;   // grid 256 -> 65536 threads
    if (g < 1040) ws32[g] = 0u;               // commitAcc + counts
    rmin[g] = 0xFFFFFFFFFFFFFFFFull;
}

// ---------------- init (fallback): zero commit+counts only ----------------
__global__ void k_initS(unsigned* ws32) {
    int g = blockIdx.x * 256 + threadIdx.x;
    if (g < 1040) ws32[g] = 0u;
}

// ---------------- codebook row norms (fp32 exact) ----------------
__global__ void k_codenorm(const float* __restrict__ cb, float* __restrict__ cnorm) {
    int j = blockIdx.x * 256 + threadIdx.x;   // grid 4 -> 1024
    const float* r = cb + (size_t)j * C_;
    float s = 0.f;
    for (int i = 0; i < C_; i += 4) {
        float4 v = *(const float4*)&r[i];
        s = fmaf(v.x, v.x, s); s = fmaf(v.y, v.y, s);
        s = fmaf(v.z, v.z, s); s = fmaf(v.w, v.w, s);
    }
    cnorm[j] = s;
}

// ---------------- codebook -> f16 hi/lo split ----------------
__global__ void k_cvt_cb(const float* __restrict__ cb,
                         _Float16* __restrict__ cbh, _Float16* __restrict__ cbl) {
    int t = blockIdx.x * 256 + threadIdx.x;   // grid 512 -> 131072, x4 elems
    float4 v = *(const float4*)&cb[(size_t)t * 4];
    h4 hi, lo;
    hi.x = (_Float16)v.x; lo.x = (_Float16)(v.x - (float)hi.x);
    hi.y = (_Float16)v.y; lo.y = (_Float16)(v.y - (float)hi.y);
    hi.z = (_Float16)v.z; lo.z = (_Float16)(v.z - (float)hi.z);
    hi.w = (_Float16)v.w; lo.w = (_Float16)(v.w - (float)hi.w);
    *(h4*)&cbh[(size_t)t * 4] = hi;
    *(h4*)&cbl[(size_t)t * 4] = lo;
}

// ---------------- x (n,c,t) -> xt[(n t)][c] f16 hi/lo split (LDS transpose) ----------------
__global__ __launch_bounds__(256)
void k_xt(const float* __restrict__ x,
          _Float16* __restrict__ xth, _Float16* __restrict__ xtl) {
    __shared__ float Ls[64 * 68];
    const int bx = blockIdx.x;                // grid 8192
    const int n = bx >> 8;
    const int cblk = (bx >> 5) & 7, tblk = bx & 31;
    const int c0 = cblk * 64, t0 = tblk * 64;
    const int tid = threadIdx.x;
    #pragma unroll
    for (int ld = 0; ld < 4; ++ld) {
        int idx = tid + ld * 256;
        int cc = idx >> 4, t4 = (idx & 15) << 2;
        float4 v = *(const float4*)&x[((size_t)n * C_ + c0 + cc) * T_ + t0 + t4];
        *(float4*)&Ls[cc * 68 + t4] = v;
    }
    __syncthreads();
    const int tt = tid >> 2, cs = (tid & 3) * 16;
    h8 hi0, hi1, lo0, lo1;
    #pragma unroll
    for (int j = 0; j < 8; ++j) {
        float f = Ls[(cs + j) * 68 + tt];
        _Float16 h = (_Float16)f;
        hi0[j] = h; lo0[j] = (_Float16)(f - (float)h);
    }
    #pragma unroll
    for (int j = 0; j < 8; ++j) {
        float f = Ls[(cs + 8 + j) * 68 + tt];
        _Float16 h = (_Float16)f;
        hi1[j] = h; lo1[j] = (_Float16)(f - (float)h);
    }
    const size_t dst = ((size_t)n * T_ + t0 + tt) * C_ + c0 + cs;
    *(h8*)&xth[dst] = hi0; *(h8*)&xth[dst + 8] = hi1;
    *(h8*)&xtl[dst] = lo0; *(h8*)&xtl[dst + 8] = lo1;
}

// ---------------- MFMA GEMM + streaming argmin ----------------
// grid 512 (one 128-row block each), block tile 128x256 over codes, 4 chunks
__global__ __launch_bounds__(256, 2)
void k_gemm(const _Float16* __restrict__ xth, const _Float16* __restrict__ xtl,
            const _Float16* __restrict__ cbh, const _Float16* __restrict__ cbl,
            const float* __restrict__ cnorm, unsigned long long* __restrict__ rmin) {
    __shared__ _Float16 sm[24576];   // Ah@0 Al@4096 Bh@8192 Bl@16384 (halfs) = 48KB
    const int tid = threadIdx.x;
    const int l = tid & 63, w = tid >> 6;
    const int q = l >> 4, r = l & 15;
    const int wm0 = (w & 1) * 64, wn0 = (w >> 1) * 128;
    const int bid = blockIdx.x;
    const int lrow = l >> 2;
    const int lcolB = (l & 3) * 16;

    // global staging addresses (bytes); row stride = 512 halfs = 1024 B
    const char* gAh = (const char*)xth + ((size_t)bid * 128 + w * 16 + lrow) * 1024 + lcolB;
    const char* gAl = (const char*)xtl + ((size_t)bid * 128 + w * 16 + lrow) * 1024 + lcolB;

    const int aoff = (wm0 + r) * 32 + q * 8;
    const int boff = (wn0 + r) * 32 + q * 8;

    for (int ch = 0; ch < 4; ++ch) {
        const int j0 = ch * 256;
        const char* gBh = (const char*)cbh + ((size_t)j0 + w * 16 + lrow) * 1024 + lcolB;
        const char* gBl = (const char*)cbl + ((size_t)j0 + w * 16 + lrow) * 1024 + lcolB;

        f4 acc[4][8];
        #pragma unroll
        for (int i = 0; i < 4; ++i)
            #pragma unroll
            for (int j = 0; j < 8; ++j)
                acc[i][j] = (f4){0.f, 0.f, 0.f, 0.f};

        for (int kb = 0; kb < 16; ++kb) {
            const int kof = kb * 64;
            __syncthreads();
            gll16(gAh + kof,         &sm[(size_t)w * 512]);
            gll16(gAh + 65536 + kof, &sm[(size_t)(4 + w) * 512]);
            gll16(gAl + kof,         &sm[4096 + (size_t)w * 512]);
            gll16(gAl + 65536 + kof, &sm[4096 + (size_t)(4 + w) * 512]);
            #pragma unroll
            for (int p = 0; p < 4; ++p) {
                gll16(gBh + (size_t)p * 65536 + kof, &sm[8192  + (size_t)(p * 4 + w) * 512]);
                gll16(gBl + (size_t)p * 65536 + kof, &sm[16384 + (size_t)(p * 4 + w) * 512]);
            }
            __syncthreads();

            h8 ah[4], al[4];
            #pragma unroll
            for (int i = 0; i < 4; ++i) {
                ah[i] = *(const h8*)&sm[aoff + i * 512];
                al[i] = *(const h8*)&sm[4096 + aoff + i * 512];
            }
            #pragma unroll
            for (int j = 0; j < 8; ++j) {
                h8 bh = *(const h8*)&sm[8192  + boff + j * 512];
                h8 bl = *(const h8*)&sm[16384 + boff + j * 512];
                #pragma unroll
                for (int i = 0; i < 4; ++i) {
                    acc[i][j] = __builtin_amdgcn_mfma_f32_16x16x32_f16(ah[i], bh, acc[i][j], 0, 0, 0);
                    acc[i][j] = __builtin_amdgcn_mfma_f32_16x16x32_f16(al[i], bh, acc[i][j], 0, 0, 0);
                    acc[i][j] = __builtin_amdgcn_mfma_f32_16x16x32_f16(ah[i], bl, acc[i][j], 0, 0, 0);
                }
            }
        }

        // streaming argmin for this chunk: score = ||k||^2 - 2*dot
        float cn[8];
        #pragma unroll
        for (int j = 0; j < 8; ++j) cn[j] = cnorm[j0 + wn0 + j * 16 + r];

        #pragma unroll
        for (int i = 0; i < 4; ++i) {
            #pragma unroll
            for (int rg = 0; rg < 4; ++rg) {
                unsigned long long best = 0xFFFFFFFFFFFFFFFFull;
                #pragma unroll
                for (int j = 0; j < 8; ++j) {
                    float s = fmaf(-2.0f, acc[i][j][rg], cn[j]);
                    unsigned u = __float_as_uint(s);
                    u = (u & 0x80000000u) ? ~u : (u | 0x80000000u);
                    unsigned long long key =
                        ((unsigned long long)u << 32) | (unsigned)(j0 + wn0 + j * 16 + r);
                    best = key < best ? key : best;
                }
                #pragma unroll
                for (int off = 1; off < 16; off <<= 1) {
                    unsigned long long o = __shfl_xor(best, off, 64);
                    best = o < best ? o : best;
                }
                if (r == 0)
                    atomicMin(&rmin[(size_t)bid * 128 + wm0 + i * 16 + q * 4 + rg], best);
            }
        }
    }
}

// ---------------- epilogue: gather + out + commit + counts ----------------
__global__ __launch_bounds__(256)
void k_post(const float* __restrict__ x, const float* __restrict__ cb,
            const unsigned long long* __restrict__ rmin,
            float* __restrict__ out, float* __restrict__ commitAcc,
            int* __restrict__ counts) {
    __shared__ float gbuf[64 * GB_S];
    __shared__ int sidx[128];
    __shared__ float red[4];
    const int bid = blockIdx.x;              // grid 512
    const int tid = threadIdx.x;
    const size_t r0 = (size_t)bid * 128;
    const int n  = (int)(r0 >> 11);
    const int t0 = (int)(r0 & 2047);
    const size_t xbase = (size_t)n * C_ * T_ + t0;

    if (tid < 128) {
        int code = (int)(rmin[r0 + tid] & 0xFFFFFFFFull);
        sidx[tid] = code;
        atomicAdd(&counts[code], 1);
    }
    __syncthreads();

    const int tl   = tid >> 1;
    const int half = tid & 1;
    const int tcol  = tid & 127;
    const int chalf = tid >> 7;
    float commit = 0.f;

    for (int c0 = 0; c0 < C_; c0 += 64) {
        __syncthreads();
        const int code = sidx[tl];
        const float* src = &cb[(size_t)code * C_ + c0 + half * 32];
        #pragma unroll
        for (int qq = 0; qq < 8; ++qq) {
            float4 v = *(const float4*)&src[qq * 4];
            const int cc = half * 32 + qq * 4;
            gbuf[(cc + 0) * GB_S + tl] = v.x;
            gbuf[(cc + 1) * GB_S + tl] = v.y;
            gbuf[(cc + 2) * GB_S + tl] = v.z;
            gbuf[(cc + 3) * GB_S + tl] = v.w;
        }
        __syncthreads();
        #pragma unroll 8
        for (int i = 0; i < 32; ++i) {
            const int cc = i * 2 + chalf;
            const size_t gidx = xbase + (size_t)(c0 + cc) * T_ + tcol;
            float g  = gbuf[cc * GB_S + tcol];
            float xv = x[gidx];
            out[gidx] = g;
            float d = xv - g;
            commit = fmaf(d, d, commit);
        }
    }

    #pragma unroll
    for (int off = 32; off; off >>= 1) commit += __shfl_down(commit, off, 64);
    if ((tid & 63) == 0) red[tid >> 6] = commit;
    __syncthreads();
    if (tid == 0) atomicAdd(commitAcc, red[0] + red[1] + red[2] + red[3]);
}

// ---------------- finalize: perplexity + commit scalars ----------------
__global__ void k_final(const int* __restrict__ counts,
                        const float* __restrict__ commitAcc,
                        float* __restrict__ out) {
    __shared__ float red[4];
    int tid = threadIdx.x;
    float s = 0.f;
    for (int j = tid; j < NB; j += 256) {
        float p = (float)counts[j] * (1.0f / (float)NT);
        s += p * logf(p + 1e-7f);
    }
    #pragma unroll
    for (int off = 32; off; off >>= 1) s += __shfl_down(s, off, 64);
    if ((tid & 63) == 0) red[tid >> 6] = s;
    __syncthreads();
    if (tid == 0) {
        float H = red[0] + red[1] + red[2] + red[3];
        out[(size_t)NT * C_]     = commitAcc[0] * (1.0f / ((float)NT * (float)C_));
        out[(size_t)NT * C_ + 1] = expf(-H);
    }
}

// ================= fallback fp32 path (proven, R1) =================
#define BM  128
#define BN  128
#define BK  16
#define AS_S 128
#define BS_S 132

__global__ __launch_bounds__(256, 4)
void k_main_fb(const float* __restrict__ x, const float* __restrict__ cb,
               const float* __restrict__ cnorm, float* __restrict__ out,
               float* __restrict__ commitAcc, int* __restrict__ counts) {
    __shared__ float smem[8256];
    __shared__ unsigned long long rmin[BM];
    __shared__ int sidx[BM];
    __shared__ float red[4];

    float* As = smem;
    float* Bs = smem + BK * AS_S;

    const int bid = blockIdx.x;
    const int n   = bid >> 4;
    const int t0  = (bid & 15) << 7;
    const int tid = threadIdx.x;
    const int tx  = tid & 15;
    const int ty  = tid >> 4;

    if (tid < BM) rmin[tid] = 0xFFFFFFFFFFFFFFFFull;

    const size_t xbase = (size_t)n * C_ * T_ + t0;

    for (int ch = 0; ch < NB / BN; ++ch) {
        const int j0 = ch * BN;
        float acc[2][2][4][4];
        #pragma unroll
        for (int a0 = 0; a0 < 2; ++a0)
            #pragma unroll
            for (int a1 = 0; a1 < 2; ++a1)
                #pragma unroll
                for (int a2 = 0; a2 < 4; ++a2)
                    #pragma unroll
                    for (int a3 = 0; a3 < 4; ++a3) acc[a0][a1][a2][a3] = 0.f;

        for (int kb = 0; kb < C_ / BK; ++kb) {
            const int k0 = kb * BK;
            __syncthreads();
            {
                const int kk = tid >> 5;
                const int m4 = (tid & 31) << 2;
                float4 a0v = *(const float4*)&x[xbase + (size_t)(k0 + kk) * T_ + m4];
                float4 a1v = *(const float4*)&x[xbase + (size_t)(k0 + kk + 8) * T_ + m4];
                *(float4*)&As[kk * AS_S + m4] = a0v;
                *(float4*)&As[(kk + 8) * AS_S + m4] = a1v;
                const int j  = tid >> 2;
                const int kq = (tid & 3) << 2;
                float4 b0v = *(const float4*)&cb[(size_t)(j0 + j) * C_ + k0 + kq];
                float4 b1v = *(const float4*)&cb[(size_t)(j0 + j + 64) * C_ + k0 + kq];
                Bs[(kq + 0) * BS_S + j] = b0v.x;
                Bs[(kq + 1) * BS_S + j] = b0v.y;
                Bs[(kq + 2) * BS_S + j] = b0v.z;
                Bs[(kq + 3) * BS_S + j] = b0v.w;
                Bs[(kq + 0) * BS_S + j + 64] = b1v.x;
                Bs[(kq + 1) * BS_S + j + 64] = b1v.y;
                Bs[(kq + 2) * BS_S + j + 64] = b1v.z;
                Bs[(kq + 3) * BS_S + j + 64] = b1v.w;
            }
            __syncthreads();
            #pragma unroll
            for (int kk = 0; kk < BK; ++kk) {
                float4 aL = *(const float4*)&As[kk * AS_S + (ty << 2)];
                float4 aH = *(const float4*)&As[kk * AS_S + 64 + (ty << 2)];
                float4 bL = *(const float4*)&Bs[kk * BS_S + (tx << 2)];
                float4 bH = *(const float4*)&Bs[kk * BS_S + 64 + (tx << 2)];
                float av[2][4] = {{aL.x, aL.y, aL.z, aL.w}, {aH.x, aH.y, aH.z, aH.w}};
                float bv[2][4] = {{bL.x, bL.y, bL.z, bL.w}, {bH.x, bH.y, bH.z, bH.w}};
                #pragma unroll
                for (int ih = 0; ih < 2; ++ih)
                    #pragma unroll
                    for (int i = 0; i < 4; ++i)
                        #pragma unroll
                        for (int jh = 0; jh < 2; ++jh)
                            #pragma unroll
                            for (int j = 0; j < 4; ++j)
                                acc[ih][jh][i][j] = fmaf(av[ih][i], bv[jh][j], acc[ih][jh][i][j]);
            }
        }

        float cnj[2][4];
        #pragma unroll
        for (int jh = 0; jh < 2; ++jh)
            #pragma unroll
            for (int j = 0; j < 4; ++j)
                cnj[jh][j] = cnorm[j0 + jh * 64 + (tx << 2) + j];

        #pragma unroll
        for (int ih = 0; ih < 2; ++ih) {
            #pragma unroll
            for (int i = 0; i < 4; ++i) {
                const int row = ih * 64 + (ty << 2) + i;
                unsigned long long best = 0xFFFFFFFFFFFFFFFFull;
                #pragma unroll
                for (int jh = 0; jh < 2; ++jh) {
                    #pragma unroll
                    for (int j = 0; j < 4; ++j) {
                        const int code = j0 + jh * 64 + (tx << 2) + j;
                        float s = fmaf(-2.0f, acc[ih][jh][i][j], cnj[jh][j]);
                        unsigned u = __float_as_uint(s);
                        u = (u & 0x80000000u) ? ~u : (u | 0x80000000u);
                        unsigned long long key =
                            ((unsigned long long)u << 32) | (unsigned)code;
                        best = key < best ? key : best;
                    }
                }
                #pragma unroll
                for (int off = 8; off; off >>= 1) {
                    unsigned long long o = __shfl_down(best, off, 16);
                    best = o < best ? o : best;
                }
                if (tx == 0) {
                    unsigned long long cur = rmin[row];
                    rmin[row] = best < cur ? best : cur;
                }
            }
        }
    }

    __syncthreads();
    if (tid < BM) {
        int code = (int)(rmin[tid] & 0xFFFFFFFFull);
        sidx[tid] = code;
        atomicAdd(&counts[code], 1);
    }
    __syncthreads();

    float* gbuf = smem;
    const int tl   = tid >> 1;
    const int half = tid & 1;
    const int tcol  = tid & 127;
    const int chalf = tid >> 7;
    float commit = 0.f;

    for (int c0 = 0; c0 < C_; c0 += 64) {
        __syncthreads();
        const int code = sidx[tl];
        const float* src = &cb[(size_t)code * C_ + c0 + half * 32];
        #pragma unroll
        for (int qq = 0; qq < 8; ++qq) {
            float4 v = *(const float4*)&src[qq * 4];
            const int cc = half * 32 + qq * 4;
            gbuf[(cc + 0) * GB_S + tl] = v.x;
            gbuf[(cc + 1) * GB_S + tl] = v.y;
            gbuf[(cc + 2) * GB_S + tl] = v.z;
            gbuf[(cc + 3) * GB_S + tl] = v.w;
        }
        __syncthreads();
        #pragma unroll 8
        for (int i = 0; i < 32; ++i) {
            const int cc = i * 2 + chalf;
            const size_t gidx = xbase + (size_t)(c0 + cc) * T_ + tcol;
            float g  = gbuf[cc * GB_S + tcol];
            float xv = x[gidx];
            out[gidx] = g;
            float d = xv - g;
            commit = fmaf(d, d, commit);
        }
    }

    #pragma unroll
    for (int off = 32; off; off >>= 1) commit += __shfl_down(commit, off, 64);
    if ((tid & 63) == 0) red[tid >> 6] = commit;
    __syncthreads();
    if (tid == 0) atomicAdd(commitAcc, red[0] + red[1] + red[2] + red[3]);
}

extern "C" void kernel_launch(void* const* d_in, const int* in_sizes, int n_in,
                              void* d_out, int out_size, void* d_ws, size_t ws_size,
                              hipStream_t stream) {
    const float* x  = (const float*)d_in[0];   // (32, 512, 2048)
    const float* cb = (const float*)d_in[1];   // (1024, 512)
    float* out = (float*)d_out;

    char* ws = (char*)d_ws;
    float* commitAcc = (float*)(ws + WS_COMMIT);
    int*   counts    = (int*)(ws + WS_COUNTS);
    float* cnorm     = (float*)(ws + WS_CNORM);
    unsigned long long* rmin = (unsigned long long*)(ws + WS_RMIN);
    _Float16* cbh = (_Float16*)(ws + WS_CBH);
    _Float16* cbl = (_Float16*)(ws + WS_CBL);
    _Float16* xth = (_Float16*)(ws + WS_XTH);
    _Float16* xtl = (_Float16*)(ws + WS_XTL);

    if (ws_size >= WS_NEED) {
        k_initA<<<256, 256, 0, stream>>>((unsigned*)ws, rmin);
        k_codenorm<<<4, 256, 0, stream>>>(cb, cnorm);
        k_cvt_cb<<<512, 256, 0, stream>>>(cb, cbh, cbl);
        k_xt<<<8192, 256, 0, stream>>>(x, xth, xtl);
        k_gemm<<<512, 256, 0, stream>>>(xth, xtl, cbh, cbl, cnorm, rmin);
        k_post<<<512, 256, 0, stream>>>(x, cb, rmin, out, commitAcc, counts);
        k_final<<<1, 256, 0, stream>>>(counts, commitAcc, out);
    } else {
        k_initS<<<5, 256, 0, stream>>>((unsigned*)ws);
        k_codenorm<<<4, 256, 0, stream>>>(cb, cnorm);
        k_main_fb<<<512, 256, 0, stream>>>(x, cb, cnorm, out, commitAcc, counts);
        k_final<<<1, 256, 0, stream>>>(counts, commitAcc, out);
    }
}